// Round 1
// baseline (547.738 us; speedup 1.0000x reference)
//
#include <hip/hip_runtime.h>
#include <stdint.h>

// TemporalAttention: windowed causal attention, B=16 T=4096 C=512 H=8 hd=64 W=128
// Strategy: bf16 MFMA pipeline (no fp32 MFMA on CDNA4).
//   cast -> QKV GEMM (m97-style global_load_lds staging) -> per-(window,head)
//   fused attention (regs softmax) -> proj GEMM + bias.
// Workspace layout (bytes):
//   x_bf16    @ 0          : 67108864   (65536 x 512 bf16)
//   qk_ws     @ 67108864   : 134217728  (65536 x 1024 bf16: cols 0-511 Q, 512-1023 K)
//   vT_ws     @ 201326592  : 67108864   (512 win x 8 h x 64 d x 128 t bf16)
//   attn_ws   @ 268435456  : 67108864   (65536 x 512 bf16)
//   wqkv_bf   @ 335544320  : 1572864
//   wproj_bf  @ 337117184  : 524288
// total ~322 MB.

typedef unsigned short ushort_t;
typedef __attribute__((ext_vector_type(8))) short short8;
typedef __attribute__((ext_vector_type(4))) float f32x4;
typedef __attribute__((ext_vector_type(4))) float f4v;
typedef __attribute__((ext_vector_type(4))) unsigned short us4;

static __device__ __forceinline__ unsigned short f2bf(float f) {
  unsigned int u = __float_as_uint(f);
  u += 0x7FFFu + ((u >> 16) & 1u);   // RNE
  return (unsigned short)(u >> 16);
}

static __device__ __forceinline__ void gl_lds16(const ushort_t* g, ushort_t* l) {
  __builtin_amdgcn_global_load_lds(
      (const __attribute__((address_space(1))) void*)g,
      (__attribute__((address_space(3))) void*)l, 16, 0, 0);
}

// ---------------- cast fp32 -> bf16 (vectorized) ----------------
__global__ __launch_bounds__(256) void cast_f32_bf16(const float* __restrict__ in,
                                                     ushort_t* __restrict__ out, int n4) {
  int i = blockIdx.x * 256 + threadIdx.x;
  if (i >= n4) return;
  f4v v = ((const f4v*)in)[i];
  us4 o;
  o.x = f2bf(v.x); o.y = f2bf(v.y); o.z = f2bf(v.z); o.w = f2bf(v.w);
  ((us4*)out)[i] = o;
}

// ---------------- QKV GEMM: [65536,512] x [1536,512]^T -> qk_ws / vT_ws ----------------
// BM=BN=128, BK=64, 256 thr (4 waves), wave -> 64x64 quadrant, 16x16x32 bf16 MFMA.
__global__ __launch_bounds__(256) void qkv_gemm(const ushort_t* __restrict__ A,
                                                const ushort_t* __restrict__ B,
                                                ushort_t* __restrict__ qk,
                                                ushort_t* __restrict__ vT) {
  __shared__ __align__(16) ushort_t As[128 * 64];
  __shared__ __align__(16) ushort_t Bs[128 * 64];
  const int tid = threadIdx.x;
  const int lane = tid & 63;
  const int wv = tid >> 6;
  const int wr = wv >> 1, wc = wv & 1;
  const int m0 = blockIdx.y << 7;
  const int n0 = blockIdx.x << 7;
  const int lr = lane & 15;
  const int lg = lane >> 4;
  const int lk = lg << 3;

  f32x4 acc[4][4] = {};

  const int grow = tid >> 3;           // 0..31
  const int gcol = (tid & 7) << 3;     // 0..56
  const ushort_t* gA = A + (size_t)(m0 + grow) * 512 + gcol;
  const ushort_t* gB = B + (size_t)(n0 + grow) * 512 + gcol;

  for (int kk = 0; kk < 512; kk += 64) {
#pragma unroll
    for (int r = 0; r < 4; ++r) {
      // chunk = r*256 + tid; LDS dest = wave-uniform base + lane*16 (no padding!)
      gl_lds16(gA + (size_t)(r * 32) * 512 + kk, As + (size_t)(r * 256 + wv * 64) * 8);
      gl_lds16(gB + (size_t)(r * 32) * 512 + kk, Bs + (size_t)(r * 256 + wv * 64) * 8);
    }
    __syncthreads();
#pragma unroll
    for (int ks = 0; ks < 2; ++ks) {
      const int kb = ks * 32 + lk;
      short8 a[4], b[4];
#pragma unroll
      for (int mi = 0; mi < 4; ++mi)
        a[mi] = *(const short8*)(As + (wr * 64 + mi * 16 + lr) * 64 + kb);
#pragma unroll
      for (int ni = 0; ni < 4; ++ni)
        b[ni] = *(const short8*)(Bs + (wc * 64 + ni * 16 + lr) * 64 + kb);
#pragma unroll
      for (int mi = 0; mi < 4; ++mi)
#pragma unroll
        for (int ni = 0; ni < 4; ++ni)
          acc[mi][ni] = __builtin_amdgcn_mfma_f32_16x16x32_bf16(a[mi], b[ni], acc[mi][ni], 0, 0, 0);
    }
    __syncthreads();
  }

  // Epilogue. C layout: col=lane&15, row=(lane>>4)*4+reg.
  if (n0 < 1024) {
    // Q / K region -> qk_ws row-major [65536][1024]
#pragma unroll
    for (int mi = 0; mi < 4; ++mi) {
      const int rbase = m0 + wr * 64 + mi * 16 + lg * 4;
#pragma unroll
      for (int ni = 0; ni < 4; ++ni) {
        const int col = n0 + wc * 64 + ni * 16 + lr;
#pragma unroll
        for (int rg = 0; rg < 4; ++rg)
          qk[(size_t)(rbase + rg) * 1024 + col] = f2bf(acc[mi][ni][rg]);
      }
    }
  } else {
    // V region -> transposed vT_ws[((win*8+h)*64+d)*128 + t]
    const int win = blockIdx.y;
#pragma unroll
    for (int mi = 0; mi < 4; ++mi) {
      const int t0 = wr * 64 + mi * 16 + lg * 4;  // t within window (4 consecutive via regs)
#pragma unroll
      for (int ni = 0; ni < 4; ++ni) {
        const int c = n0 - 1024 + wc * 64 + ni * 16 + lr;  // 0..511
        const int h = c >> 6, d = c & 63;
        us4 o;
        o.x = f2bf(acc[mi][ni][0]); o.y = f2bf(acc[mi][ni][1]);
        o.z = f2bf(acc[mi][ni][2]); o.w = f2bf(acc[mi][ni][3]);
        *(us4*)(vT + (size_t)((win * 8 + h) * 64 + d) * 128 + t0) = o;
      }
    }
  }
}

// ---------------- fused windowed causal attention ----------------
// 1 block per (window, head). 256 thr, 4 waves; wave w owns query rows [32w, 32w+32).
// LDS: q[128][72] @0, k[128][72] @9216, P[128][136] overlays @0, vT[64][136] @18432.
__global__ __launch_bounds__(256) void attn_kernel(const ushort_t* __restrict__ qk,
                                                   const ushort_t* __restrict__ vT,
                                                   ushort_t* __restrict__ attn_out) {
  __shared__ __align__(16) ushort_t smem[27136];
  ushort_t* qs = smem;
  ushort_t* ks_ = smem + 9216;
  ushort_t* ps = smem;          // overlay (written after barrier)
  ushort_t* vs = smem + 18432;

  const int tid = threadIdx.x;
  const int lane = tid & 63;
  const int wv = tid >> 6;
  const int win = blockIdx.x >> 3;
  const int h = blockIdx.x & 7;
  const int lr = lane & 15;
  const int lg = lane >> 4;
  const int lk = lg << 3;

  // --- stage q, k (row-major, pad to 72) and vT (row-major [64][128+8]) ---
  const size_t qbase = (size_t)win * 128 * 1024 + h * 64;
#pragma unroll
  for (int r = 0; r < 4; ++r) {
    const int c = r * 256 + tid;       // 0..1023
    const int t = c >> 3, d8 = (c & 7) << 3;
    short8 vq = *(const short8*)(qk + qbase + (size_t)t * 1024 + d8);
    short8 vk = *(const short8*)(qk + qbase + 512 + (size_t)t * 1024 + d8);
    *(short8*)(qs + t * 72 + d8) = vq;
    *(short8*)(ks_ + t * 72 + d8) = vk;
  }
  const size_t vbase = (size_t)(win * 8 + h) * 64 * 128;
#pragma unroll
  for (int r = 0; r < 4; ++r) {
    const int c = r * 256 + tid;
    const int d = c >> 4, t8 = (c & 15) << 3;
    short8 vvv = *(const short8*)(vT + vbase + (size_t)d * 128 + t8);
    *(short8*)(vs + d * 136 + t8) = vvv;
  }
  __syncthreads();

  // --- S = q k^T (only lower-triangle col tiles) ---
  const int r0 = wv * 32;
  const int ncol = 2 * (wv + 1);     // active 16-wide col tiles
  f32x4 sacc[2][8] = {};
#pragma unroll
  for (int ks2 = 0; ks2 < 2; ++ks2) {
    const int kb = ks2 * 32 + lk;
    short8 a0 = *(const short8*)(qs + (r0 + lr) * 72 + kb);
    short8 a1 = *(const short8*)(qs + (r0 + 16 + lr) * 72 + kb);
#pragma unroll
    for (int ni = 0; ni < 8; ++ni) {
      if (ni < ncol) {
        short8 b = *(const short8*)(ks_ + (ni * 16 + lr) * 72 + kb);
        sacc[0][ni] = __builtin_amdgcn_mfma_f32_16x16x32_bf16(a0, b, sacc[0][ni], 0, 0, 0);
        sacc[1][ni] = __builtin_amdgcn_mfma_f32_16x16x32_bf16(a1, b, sacc[1][ni], 0, 0, 0);
      }
    }
  }

  // --- mask + softmax in registers. Row r lives in one 16-lane group. ---
  const float scale = 0.125f;
  float rs[2][4];
#pragma unroll
  for (int mi = 0; mi < 2; ++mi) {
#pragma unroll
    for (int rg = 0; rg < 4; ++rg) {
      const int row = r0 + mi * 16 + lg * 4 + rg;
      float m = -1e30f;
#pragma unroll
      for (int ni = 0; ni < 8; ++ni) {
        if (ni < ncol) {
          const int col = ni * 16 + lr;
          float v = sacc[mi][ni][rg] * scale;
          v = (col <= row) ? v : -1e30f;
          sacc[mi][ni][rg] = v;
          m = fmaxf(m, v);
        }
      }
      m = fmaxf(m, __shfl_xor(m, 1));
      m = fmaxf(m, __shfl_xor(m, 2));
      m = fmaxf(m, __shfl_xor(m, 4));
      m = fmaxf(m, __shfl_xor(m, 8));
      float s = 0.f;
#pragma unroll
      for (int ni = 0; ni < 8; ++ni) {
        if (ni < ncol) {
          float p = __expf(sacc[mi][ni][rg] - m);
          sacc[mi][ni][rg] = p;
          s += p;
        }
      }
      s += __shfl_xor(s, 1);
      s += __shfl_xor(s, 2);
      s += __shfl_xor(s, 4);
      s += __shfl_xor(s, 8);
      rs[mi][rg] = 1.0f / s;
    }
  }

  __syncthreads();  // all waves done reading q/k before P overlays them

  // --- write unnormalized P (bf16) into LDS, padded stride 136 ---
#pragma unroll
  for (int mi = 0; mi < 2; ++mi)
#pragma unroll
    for (int ni = 0; ni < 8; ++ni) {
      if (ni < ncol) {
#pragma unroll
        for (int rg = 0; rg < 4; ++rg) {
          const int row = r0 + mi * 16 + lg * 4 + rg;
          const int col = ni * 16 + lr;
          ps[row * 136 + col] = f2bf(sacc[mi][ni][rg]);
        }
      }
    }
  // each wave reads back only its own P rows -> no second barrier needed

  // --- O = P V (skip fully-masked k-steps) ---
  f32x4 oacc[2][4] = {};
#pragma unroll
  for (int ks2 = 0; ks2 < 4; ++ks2) {
    if (ks2 <= wv) {
      const int kb = ks2 * 32 + lk;
      short8 a0 = *(const short8*)(ps + (r0 + lr) * 136 + kb);
      short8 a1 = *(const short8*)(ps + (r0 + 16 + lr) * 136 + kb);
#pragma unroll
      for (int nd = 0; nd < 4; ++nd) {
        short8 b = *(const short8*)(vs + (nd * 16 + lr) * 136 + kb);
        oacc[0][nd] = __builtin_amdgcn_mfma_f32_16x16x32_bf16(a0, b, oacc[0][nd], 0, 0, 0);
        oacc[1][nd] = __builtin_amdgcn_mfma_f32_16x16x32_bf16(a1, b, oacc[1][nd], 0, 0, 0);
      }
    }
  }

  // --- epilogue: normalize by row-sum, store bf16 [65536][512], col = h*64+d ---
  const size_t obase = (size_t)win * 128 * 512 + h * 64;
#pragma unroll
  for (int mi = 0; mi < 2; ++mi)
#pragma unroll
    for (int nd = 0; nd < 4; ++nd)
#pragma unroll
      for (int rg = 0; rg < 4; ++rg) {
        const int row = r0 + mi * 16 + lg * 4 + rg;
        const int col = nd * 16 + lr;
        attn_out[obase + (size_t)row * 512 + col] = f2bf(oacc[mi][nd][rg] * rs[mi][rg]);
      }
}

// ---------------- proj GEMM: [65536,512] x [512,512]^T + bias -> fp32 out ----------------
__global__ __launch_bounds__(256) void proj_gemm(const ushort_t* __restrict__ A,
                                                 const ushort_t* __restrict__ B,
                                                 const float* __restrict__ bias,
                                                 float* __restrict__ out) {
  __shared__ __align__(16) ushort_t As[128 * 64];
  __shared__ __align__(16) ushort_t Bs[128 * 64];
  const int tid = threadIdx.x;
  const int lane = tid & 63;
  const int wv = tid >> 6;
  const int wr = wv >> 1, wc = wv & 1;
  const int m0 = blockIdx.y << 7;
  const int n0 = blockIdx.x << 7;
  const int lr = lane & 15;
  const int lg = lane >> 4;
  const int lk = lg << 3;

  f32x4 acc[4][4] = {};

  const int grow = tid >> 3;
  const int gcol = (tid & 7) << 3;
  const ushort_t* gA = A + (size_t)(m0 + grow) * 512 + gcol;
  const ushort_t* gB = B + (size_t)(n0 + grow) * 512 + gcol;

  for (int kk = 0; kk < 512; kk += 64) {
#pragma unroll
    for (int r = 0; r < 4; ++r) {
      gl_lds16(gA + (size_t)(r * 32) * 512 + kk, As + (size_t)(r * 256 + wv * 64) * 8);
      gl_lds16(gB + (size_t)(r * 32) * 512 + kk, Bs + (size_t)(r * 256 + wv * 64) * 8);
    }
    __syncthreads();
#pragma unroll
    for (int ks = 0; ks < 2; ++ks) {
      const int kb = ks * 32 + lk;
      short8 a[4], b[4];
#pragma unroll
      for (int mi = 0; mi < 4; ++mi)
        a[mi] = *(const short8*)(As + (wr * 64 + mi * 16 + lr) * 64 + kb);
#pragma unroll
      for (int ni = 0; ni < 4; ++ni)
        b[ni] = *(const short8*)(Bs + (wc * 64 + ni * 16 + lr) * 64 + kb);
#pragma unroll
      for (int mi = 0; mi < 4; ++mi)
#pragma unroll
        for (int ni = 0; ni < 4; ++ni)
          acc[mi][ni] = __builtin_amdgcn_mfma_f32_16x16x32_bf16(a[mi], b[ni], acc[mi][ni], 0, 0, 0);
    }
    __syncthreads();
  }

#pragma unroll
  for (int mi = 0; mi < 4; ++mi) {
    const int rbase = m0 + wr * 64 + mi * 16 + lg * 4;
#pragma unroll
    for (int ni = 0; ni < 4; ++ni) {
      const int col = n0 + wc * 64 + ni * 16 + lr;
      const float bv = bias[col];
#pragma unroll
      for (int rg = 0; rg < 4; ++rg)
        out[(size_t)(rbase + rg) * 512 + col] = acc[mi][ni][rg] + bv;
    }
  }
}

extern "C" void kernel_launch(void* const* d_in, const int* in_sizes, int n_in,
                              void* d_out, int out_size, void* d_ws, size_t ws_size,
                              hipStream_t stream) {
  const float* x      = (const float*)d_in[0];
  const float* w_qkv  = (const float*)d_in[1];
  const float* w_proj = (const float*)d_in[2];
  const float* b_proj = (const float*)d_in[3];
  float* out = (float*)d_out;

  char* ws = (char*)d_ws;
  ushort_t* x_bf     = (ushort_t*)(ws);
  ushort_t* qk_ws    = (ushort_t*)(ws + 67108864);
  ushort_t* vT_ws    = (ushort_t*)(ws + 67108864 + 134217728);
  ushort_t* attn_ws  = (ushort_t*)(ws + 67108864 + 134217728 + 67108864);
  ushort_t* wqkv_bf  = (ushort_t*)(ws + 335544320);
  ushort_t* wproj_bf = (ushort_t*)(ws + 337117184);

  cast_f32_bf16<<<32768, 256, 0, stream>>>(x, x_bf, 8388608);       // 33554432/4
  cast_f32_bf16<<<768, 256, 0, stream>>>(w_qkv, wqkv_bf, 196608);   // 786432/4
  cast_f32_bf16<<<256, 256, 0, stream>>>(w_proj, wproj_bf, 65536);  // 262144/4

  qkv_gemm<<<dim3(12, 512), 256, 0, stream>>>(x_bf, wqkv_bf, qk_ws, vT_ws);
  attn_kernel<<<4096, 256, 0, stream>>>(qk_ws, vT_ws, attn_ws);
  proj_gemm<<<dim3(4, 512), 256, 0, stream>>>(attn_ws, wproj_bf, b_proj, out);
}